// Round 6
// baseline (488.506 us; speedup 1.0000x reference)
//
#include <hip/hip_runtime.h>
#include <cstdint>

#define BB   2
#define SQ   2048
#define IND  512
#define NH   8
#define DK   64
#define KNN  32
#define ODIM 512

typedef unsigned int u32;
typedef float f32x4  __attribute__((ext_vector_type(4)));
typedef short bf16x8 __attribute__((ext_vector_type(8)));

// ---------- monotone fp32 <-> uint key (order-preserving) ----------
__device__ __forceinline__ u32 f2key(float f) {
  u32 b = __float_as_uint(f);
  return (b & 0x80000000u) ? ~b : (b | 0x80000000u);
}
__device__ __forceinline__ float key2f(u32 k) {
  u32 b = (k & 0x80000000u) ? (k & 0x7fffffffu) : ~k;
  return __uint_as_float(b);
}
// ---------- fp32 -> bf16 (RTNE) and back, via bit ops ----------
__device__ __forceinline__ unsigned short f2bf(float f) {
  u32 b = __float_as_uint(f);
  b += 0x7fffu + ((b >> 16) & 1u);
  return (unsigned short)(b >> 16);
}
__device__ __forceinline__ float bf2f(unsigned short s) {
  return __uint_as_float(((u32)s) << 16);
}

#define MFMA(A, B, C) __builtin_amdgcn_mfma_f32_16x16x32_bf16(A, B, C, 0, 0, 0)

// =====================================================================
// Kernel 1: per-head K/V projection.  k = x@Wk + bk (split h/m/l bf16),
// v = x@Wv + bv (fp32).  grid = B*H*(S/64), block 256.
// =====================================================================
__global__ __launch_bounds__(256) void proj_kernel(
    const float* __restrict__ x, const float* __restrict__ Wk, const float* __restrict__ bk,
    const float* __restrict__ Wv, const float* __restrict__ bv,
    unsigned short* __restrict__ kh, unsigned short* __restrict__ km,
    unsigned short* __restrict__ kl, float* __restrict__ vout) {
  int bid  = blockIdx.x;
  int sblk = bid & 31;          // S/64 = 32
  int bh   = bid >> 5;
  int h    = bh & 7;
  int b    = bh >> 3;
  int s0   = sblk * 64;
  int tid  = threadIdx.x;

  __shared__ float xs[64][65];
  __shared__ float ws[64][132];   // row stride 528B = 33*16 -> float4-aligned

  const float* xb  = x  + ((size_t)b * SQ + s0) * IND;
  const float* wkh = Wk + (size_t)h * IND * DK;
  const float* wvh = Wv + (size_t)h * IND * DK;

  int tx = tid & 31, ty = tid >> 5;   // 32 col-groups x 8 row-groups
  float acc[8][4] = {};

  for (int d0 = 0; d0 < IND; d0 += 64) {
    __syncthreads();
    #pragma unroll
    for (int q = 0; q < 16; ++q) {
      int idx = tid + q * 256;
      int r = idx >> 6, c = idx & 63;
      xs[r][c] = xb[(size_t)r * IND + d0 + c];
    }
    #pragma unroll
    for (int q = 0; q < 32; ++q) {
      int idx = tid + q * 256;
      int r = idx >> 7, c = idx & 127;
      ws[r][c] = (c < 64) ? wkh[(size_t)(d0 + r) * DK + c]
                          : wvh[(size_t)(d0 + r) * DK + (c - 64)];
    }
    __syncthreads();
    for (int dd = 0; dd < 64; ++dd) {
      float4 wc = *(const float4*)&ws[dd][tx * 4];
      #pragma unroll
      for (int rr = 0; rr < 8; ++rr) {
        float a = xs[ty * 8 + rr][dd];
        acc[rr][0] += a * wc.x; acc[rr][1] += a * wc.y;
        acc[rr][2] += a * wc.z; acc[rr][3] += a * wc.w;
      }
    }
  }

  bool isK = (tx < 16);
  int  c0  = (tx * 4) & 63;
  if (isK) {
    float4 bb = *(const float4*)&bk[h * DK + c0];
    #pragma unroll
    for (int rr = 0; rr < 8; ++rr) {
      int srow = s0 + ty * 8 + rr;
      size_t base = (((size_t)bh) * SQ + srow) * DK + c0;
      ushort4 h4, m4, l4;
      #pragma unroll
      for (int c = 0; c < 4; ++c) {
        float val = acc[rr][c] + (&bb.x)[c];
        unsigned short hh = f2bf(val);       float fh = bf2f(hh);
        float r1 = val - fh;                 // near-exact residual
        unsigned short mm = f2bf(r1);        float fm = bf2f(mm);
        unsigned short ll = f2bf(r1 - fm);
        (&h4.x)[c] = hh; (&m4.x)[c] = mm; (&l4.x)[c] = ll;
      }
      *(ushort4*)&kh[base] = h4;
      *(ushort4*)&km[base] = m4;
      *(ushort4*)&kl[base] = l4;
    }
  } else {
    float4 bb = *(const float4*)&bv[h * DK + c0];
    #pragma unroll
    for (int rr = 0; rr < 8; ++rr) {
      int srow = s0 + ty * 8 + rr;
      size_t base = (((size_t)bh) * SQ + srow) * DK + c0;
      float4 o;
      o.x = acc[rr][0] + bb.x; o.y = acc[rr][1] + bb.y;
      o.z = acc[rr][2] + bb.z; o.w = acc[rr][3] + bb.w;
      *(float4*)&vout[base] = o;
    }
  }
}

// =====================================================================
// per-row exact top-KNN: bit-descent radix select -> p = exact
// target-th largest key; keep all keys > p plus the lowest-j ties at p
// (matches jax.lax.top_k stable tie semantics).  Then softmax over
// survivors and weighted V accumulate, h/m bf16 split output.
// =====================================================================
__device__ __forceinline__ void process_row(const u32 (&key)[KNN], int irow, int lane,
                                            float2* srow, const float* __restrict__ vb,
                                            unsigned short* __restrict__ yhd,
                                            unsigned short* __restrict__ ymd) {
  int target = min(KNN, irow + 1);
  // ---- bit-descent: p = target-th largest key (or early-exit when the
  //      prefix-count hits target exactly; then {>=p} is exactly the set)
  u32 p = 0u;
  for (int bit = 31; bit >= 0; --bit) {
    u32 mid = p | (1u << bit);
    int c = 0;
    #pragma unroll
    for (int t = 0; t < KNN; ++t)
      c += (int)__popcll(__ballot(key[t] >= mid));
    if (c >= target) { p = mid; if (c == target) break; }
  }
  // ---- row max (always a survivor) for stable softmax
  u32 mk = 0u;
  #pragma unroll
  for (int t = 0; t < KNN; ++t) mk = key[t] > mk ? key[t] : mk;
  #pragma unroll
  for (int off = 32; off >= 1; off >>= 1) { u32 o = __shfl_xor(mk, off); mk = o > mk ? o : mk; }
  float M = key2f(mk);
  // ---- G = |{key > p}|; keep (target - G) ties (== p) in ascending-j order
  int G = 0;
  #pragma unroll
  for (int t = 0; t < KNN; ++t)
    G += (int)__popcll(__ballot(key[t] > p));
  int eqAllow = target - G;
  // ---- compact survivors (w = exp(s-M), j) into LDS; exactly `target` kept
  int base = 0, eqbase = 0;
  #pragma unroll
  for (int t = 0; t < KNN; ++t) {
    bool gt = key[t] > p;
    bool eq = key[t] == p;                   // p > 0, invalid keys (0) never tie
    unsigned long long em = __ballot(eq);
    int eqrank = eqbase + (int)__popcll(em & ((1ull << lane) - 1ull));
    bool pred = gt || (eq && (eqrank < eqAllow));
    unsigned long long mm = __ballot(pred);
    int rank = (int)__popcll(mm & ((1ull << lane) - 1ull));
    if (pred) {
      int pos = base + rank;                 // pos < target <= KNN guaranteed
      float w = __expf(key2f(key[t]) - M);
      srow[pos] = make_float2(w, __int_as_float(t * 64 + lane));
    }
    base   += (int)__popcll(mm);
    eqbase += (int)__popcll(em);
  }
  // ---- y = sum w * v[j][:] / den; slots [target..KNN) pre-cleared to w=0
  float y = 0.f, den = 0.f;
  #pragma unroll
  for (int q = 0; q < KNN; ++q) {
    float2 wj = srow[q];
    float w = wj.x;
    int  j  = __float_as_int(wj.y);
    den += w;
    y   += w * vb[(size_t)j * DK + lane];
  }
  float yv = y / den;
  unsigned short hh = f2bf(yv);
  yhd[lane] = hh;
  ymd[lane] = f2bf(yv - bf2f(hh));
}

// =====================================================================
// Kernel 2: MFMA (3-way bf16 split, 16 MFMAs = all terms except l*l)
// scores + causal + exact top-32 + softmax + att@v.
// block = 512 (8 waves), 16 q-rows/block, j-tiles of 128, B-frags
// double-buffered one tile ahead (statically named regs, no runtime idx).
// =====================================================================
#define LOADB(t, B0_,B1_,B2_,B3_,B4_,B5_) { \
    size_t brow_ = (size_t)(((t) << 7) + jcol) * DK; \
    B0_ = *(const bf16x8*)(khb0 + brow_); \
    B1_ = *(const bf16x8*)(khb1 + brow_); \
    B2_ = *(const bf16x8*)(kmb0 + brow_); \
    B3_ = *(const bf16x8*)(kmb1 + brow_); \
    B4_ = *(const bf16x8*)(klb0 + brow_); \
    B5_ = *(const bf16x8*)(klb1 + brow_); \
  }

#define SCORE_STEP(t, BH0,BH1,BM0,BM1,BL0,BL1, NH0,NH1,NM0,NM1,NL0,NL1) \
  if ((t) <= tmax) { \
    f32x4 D = {0.f, 0.f, 0.f, 0.f}; \
    D = MFMA(Ah0, BH0, D); D = MFMA(Ah1, BH1, D); \
    D = MFMA(Am0, BH0, D); D = MFMA(Am1, BH1, D); \
    D = MFMA(Ah0, BM0, D); D = MFMA(Ah1, BM1, D); \
    D = MFMA(Al0, BH0, D); D = MFMA(Al1, BH1, D); \
    D = MFMA(Ah0, BL0, D); D = MFMA(Ah1, BL1, D); \
    D = MFMA(Am0, BM0, D); D = MFMA(Am1, BM1, D); \
    D = MFMA(Al0, BM0, D); D = MFMA(Al1, BM1, D); \
    D = MFMA(Am0, BL0, D); D = MFMA(Am1, BL1, D); \
    if ((t) + 1 <= tmax) LOADB((t) + 1, NH0,NH1,NM0,NM1,NL0,NL1); \
    __syncthreads(); \
    sc[ac * 4 + 0][jcol] = D[0]; sc[ac * 4 + 1][jcol] = D[1]; \
    sc[ac * 4 + 2][jcol] = D[2]; sc[ac * 4 + 3][jcol] = D[3]; \
    __syncthreads(); \
    { \
      float v0a = sc[wv * 2 + 0][lane];      float v1a = sc[wv * 2 + 1][lane]; \
      float v0b = sc[wv * 2 + 0][64 + lane]; float v1b = sc[wv * 2 + 1][64 + lane]; \
      int j0 = (t) * 128 + lane; \
      if (j0 <= q0)          key0[2*(t)]     = f2key(0.125f * v0a); \
      if (j0 <= q0 + 1)      key1[2*(t)]     = f2key(0.125f * v1a); \
      if (j0 + 64 <= q0)     key0[2*(t) + 1] = f2key(0.125f * v0b); \
      if (j0 + 64 <= q0 + 1) key1[2*(t) + 1] = f2key(0.125f * v1b); \
    } \
  }

__global__ __launch_bounds__(512) void attn_kernel(
    const unsigned short* __restrict__ kh, const unsigned short* __restrict__ km,
    const unsigned short* __restrict__ kl, const float* __restrict__ vbuf,
    unsigned short* __restrict__ yh, unsigned short* __restrict__ ym) {
  int bid  = blockIdx.x;
  int rb   = 127 - (bid & 127);        // heavy (large i0) blocks first
  int bh   = bid >> 7;
  int i0   = rb * 16;
  int tid  = threadIdx.x;
  int wv   = tid >> 6, lane = tid & 63;
  int q0   = i0 + wv * 2;

  const unsigned short* khb = kh + (size_t)bh * SQ * DK;
  const unsigned short* kmb = km + (size_t)bh * SQ * DK;
  const unsigned short* klb = kl + (size_t)bh * SQ * DK;
  const float*          vb  = vbuf + (size_t)bh * SQ * DK;

  __shared__ float  sc[16][132];          // score tile; write/read <=2-way banks
  __shared__ float2 surv[8][2][KNN + 2];

  if (lane < KNN) {
    surv[wv][0][lane] = make_float2(0.f, 0.f);
    surv[wv][1][lane] = make_float2(0.f, 0.f);
  }

  // ---- A-frags: block's 16 q-rows (q == k), 3 precisions x 2 k-steps
  int am = lane & 15, ac = lane >> 4;
  size_t arow = (size_t)(i0 + am) * DK;
  bf16x8 Ah0 = *(const bf16x8*)(khb + arow +      ac * 8);
  bf16x8 Ah1 = *(const bf16x8*)(khb + arow + 32 + ac * 8);
  bf16x8 Am0 = *(const bf16x8*)(kmb + arow +      ac * 8);
  bf16x8 Am1 = *(const bf16x8*)(kmb + arow + 32 + ac * 8);
  bf16x8 Al0 = *(const bf16x8*)(klb + arow +      ac * 8);
  bf16x8 Al1 = *(const bf16x8*)(klb + arow + 32 + ac * 8);

  u32 key0[KNN], key1[KNN];
  #pragma unroll
  for (int t = 0; t < KNN; ++t) { key0[t] = 0u; key1[t] = 0u; }

  int tmax = (i0 + 15) >> 7;           // block-uniform: barriers inside are safe
  int jcol = wv * 16 + am;             // this lane's j-col within the 128-wide tile

  // per-lane base pointers (fold in the k-chunk offset ac*8)
  const unsigned short* khb0 = khb + ac * 8;
  const unsigned short* khb1 = khb + 32 + ac * 8;
  const unsigned short* kmb0 = kmb + ac * 8;
  const unsigned short* kmb1 = kmb + 32 + ac * 8;
  const unsigned short* klb0 = klb + ac * 8;
  const unsigned short* klb1 = klb + 32 + ac * 8;

  bf16x8 Ba0, Ba1, Ba2, Ba3, Ba4, Ba5;
  bf16x8 Bb0, Bb1, Bb2, Bb3, Bb4, Bb5;
  LOADB(0, Ba0, Ba1, Ba2, Ba3, Ba4, Ba5);

  SCORE_STEP( 0, Ba0,Ba1,Ba2,Ba3,Ba4,Ba5, Bb0,Bb1,Bb2,Bb3,Bb4,Bb5)
  SCORE_STEP( 1, Bb0,Bb1,Bb2,Bb3,Bb4,Bb5, Ba0,Ba1,Ba2,Ba3,Ba4,Ba5)
  SCORE_STEP( 2, Ba0,Ba1,Ba2,Ba3,Ba4,Ba5, Bb0,Bb1,Bb2,Bb3,Bb4,Bb5)
  SCORE_STEP( 3, Bb0,Bb1,Bb2,Bb3,Bb4,Bb5, Ba0,Ba1,Ba2,Ba3,Ba4,Ba5)
  SCORE_STEP( 4, Ba0,Ba1,Ba2,Ba3,Ba4,Ba5, Bb0,Bb1,Bb2,Bb3,Bb4,Bb5)
  SCORE_STEP( 5, Bb0,Bb1,Bb2,Bb3,Bb4,Bb5, Ba0,Ba1,Ba2,Ba3,Ba4,Ba5)
  SCORE_STEP( 6, Ba0,Ba1,Ba2,Ba3,Ba4,Ba5, Bb0,Bb1,Bb2,Bb3,Bb4,Bb5)
  SCORE_STEP( 7, Bb0,Bb1,Bb2,Bb3,Bb4,Bb5, Ba0,Ba1,Ba2,Ba3,Ba4,Ba5)
  SCORE_STEP( 8, Ba0,Ba1,Ba2,Ba3,Ba4,Ba5, Bb0,Bb1,Bb2,Bb3,Bb4,Bb5)
  SCORE_STEP( 9, Bb0,Bb1,Bb2,Bb3,Bb4,Bb5, Ba0,Ba1,Ba2,Ba3,Ba4,Ba5)
  SCORE_STEP(10, Ba0,Ba1,Ba2,Ba3,Ba4,Ba5, Bb0,Bb1,Bb2,Bb3,Bb4,Bb5)
  SCORE_STEP(11, Bb0,Bb1,Bb2,Bb3,Bb4,Bb5, Ba0,Ba1,Ba2,Ba3,Ba4,Ba5)
  SCORE_STEP(12, Ba0,Ba1,Ba2,Ba3,Ba4,Ba5, Bb0,Bb1,Bb2,Bb3,Bb4,Bb5)
  SCORE_STEP(13, Bb0,Bb1,Bb2,Bb3,Bb4,Bb5, Ba0,Ba1,Ba2,Ba3,Ba4,Ba5)
  SCORE_STEP(14, Ba0,Ba1,Ba2,Ba3,Ba4,Ba5, Bb0,Bb1,Bb2,Bb3,Bb4,Bb5)
  SCORE_STEP(15, Bb0,Bb1,Bb2,Bb3,Bb4,Bb5, Ba0,Ba1,Ba2,Ba3,Ba4,Ba5)

  size_t yb0 = ((size_t)bh * SQ + q0) * DK;
  process_row(key0, q0,     lane, &surv[wv][0][0], vb, yh + yb0,      ym + yb0);
  process_row(key1, q0 + 1, lane, &surv[wv][1][0], vb, yh + yb0 + DK, ym + yb0 + DK);
}

// =====================================================================
// Kernel 4: Wo -> transposed h/m bf16 split.  wth/wtm[n][k] = split(Wo[k][n]).
// grid = 64 (8x8 tiles of 64x64), block 256.
// =====================================================================
__global__ __launch_bounds__(256) void wo_split(
    const float* __restrict__ Wo, unsigned short* __restrict__ wth,
    unsigned short* __restrict__ wtm) {
  int bid = blockIdx.x;
  int kb = bid >> 3, nb = bid & 7;
  int k0 = kb * 64, n0 = nb * 64;
  int tid = threadIdx.x;
  __shared__ float t[64][65];
  #pragma unroll
  for (int q = 0; q < 16; ++q) {
    int idx = tid + q * 256;
    int r = idx >> 6, c = idx & 63;
    t[r][c] = Wo[(size_t)(k0 + r) * ODIM + n0 + c];
  }
  __syncthreads();
  #pragma unroll
  for (int q = 0; q < 16; ++q) {
    int idx = tid + q * 256;
    int r = idx >> 6, c = idx & 63;    // r -> n offset, c -> k offset
    float v = t[c][r];                  // banks (c+r)%32: 2-way, free
    unsigned short hh = f2bf(v);
    size_t a = (size_t)(n0 + r) * ODIM + k0 + c;
    wth[a] = hh;
    wtm[a] = f2bf(v - bf2f(hh));
  }
}

// =====================================================================
// Kernel 3: output projection via MFMA (2x2 bf16 split, direct global
// loads, no LDS).  out[m][n] = sum_k y[m][k] * Wo[k][n] + bo[n],
// y = yh+ym (per-head layout), WoT = wth+wtm [n][k].
// M = 4096, N = 512, K = 512.  grid (64 m-blk)x(8 n-blk)=512, block 256.
// =====================================================================
__global__ __launch_bounds__(256) void out_gemm(
    const unsigned short* __restrict__ yh, const unsigned short* __restrict__ ym,
    const unsigned short* __restrict__ wth, const unsigned short* __restrict__ wtm,
    const float* __restrict__ bo, float* __restrict__ out) {
  int bid  = blockIdx.x;
  int nblk = bid & 7;
  int mblk = bid >> 3;
  int m0 = mblk * 64, n0 = nblk * 64;
  int tid = threadIdx.x, wv = tid >> 6, lane = tid & 63;
  int am = lane & 15, ac = lane >> 4;

  int m = m0 + wv * 16 + am;           // A-frag row for this lane
  int b = m >> 11, s = m & (SQ - 1);

  f32x4 acc[4] = {{0.f,0.f,0.f,0.f},{0.f,0.f,0.f,0.f},
                  {0.f,0.f,0.f,0.f},{0.f,0.f,0.f,0.f}};

  #pragma unroll
  for (int k0 = 0; k0 < ODIM; k0 += 32) {
    int h  = k0 >> 6;                  // head for this K-slab
    int d0 = (k0 & 63) + ac * 8;       // k-chunk within head
    size_t ya = (((size_t)(b * NH + h)) * SQ + s) * DK + d0;
    bf16x8 Ah = *(const bf16x8*)(yh + ya);
    bf16x8 Am = *(const bf16x8*)(ym + ya);
    #pragma unroll
    for (int cf = 0; cf < 4; ++cf) {
      int n = n0 + cf * 16 + am;       // B-frag col for this lane
      size_t wa = (size_t)n * ODIM + k0 + ac * 8;
      bf16x8 Bh = *(const bf16x8*)(wth + wa);
      bf16x8 Bm = *(const bf16x8*)(wtm + wa);
      acc[cf] = MFMA(Ah, Bh, acc[cf]);
      acc[cf] = MFMA(Ah, Bm, acc[cf]);
      acc[cf] = MFMA(Am, Bh, acc[cf]);
      acc[cf] = MFMA(Am, Bm, acc[cf]);
    }
  }

  // D-frag: col = lane&15 (n), row = ac*4 + r (m within the wave's 16)
  #pragma unroll
  for (int cf = 0; cf < 4; ++cf) {
    int n = n0 + cf * 16 + am;
    float bias = bo[n];
    #pragma unroll
    for (int r = 0; r < 4; ++r) {
      int mo = m0 + wv * 16 + ac * 4 + r;
      out[(size_t)mo * ODIM + n] = acc[cf][r] + bias;
    }
  }
}

// =====================================================================
extern "C" void kernel_launch(void* const* d_in, const int* in_sizes, int n_in,
                              void* d_out, int out_size, void* d_ws, size_t ws_size,
                              hipStream_t stream) {
  const float* x  = (const float*)d_in[0];
  const float* Wk = (const float*)d_in[1];
  const float* bk = (const float*)d_in[2];
  const float* Wv = (const float*)d_in[3];
  const float* bv = (const float*)d_in[4];
  const float* Wo = (const float*)d_in[5];
  const float* bo = (const float*)d_in[6];
  float* out = (float*)d_out;

  const size_t BHSD = (size_t)BB * NH * SQ * DK;   // 2,097,152 elements
  unsigned short* kh  = (unsigned short*)d_ws;
  unsigned short* km  = kh + BHSD;
  unsigned short* kl  = km + BHSD;
  float*          vbf = (float*)(kl + BHSD);       // byte off 12MB, 16B-aligned
  unsigned short* yh  = (unsigned short*)(vbf + BHSD);   // 20MB
  unsigned short* ym  = yh + BHSD;                       // 24MB
  unsigned short* wth = ym + BHSD;                       // 28MB
  unsigned short* wtm = wth + (size_t)ODIM * ODIM;       // 28.5MB (end 29MB)

  proj_kernel<<<BB * NH * (SQ / 64), 256, 0, stream>>>(x, Wk, bk, Wv, bv, kh, km, kl, vbf);
  wo_split<<<64, 256, 0, stream>>>(Wo, wth, wtm);
  attn_kernel<<<BB * NH * (SQ / 16), 512, 0, stream>>>(kh, km, kl, vbf, yh, ym);
  out_gemm<<<(BB * SQ / 64) * (ODIM / 64), 256, 0, stream>>>(yh, ym, wth, wtm, bo, out);
}